// Round 16
// baseline (643.357 us; speedup 1.0000x reference)
//
#include <hip/hip_runtime.h>
#include <math.h>

#define N_PTS 8192
#define ICP_STEPS 21      // STEPLIM + 1 scan iterations
#define ICP_TOL 1e-4

// NN geometry (R13-proven): 4 query-groups (2048 q) x 64 cand-slices (128 c)
#define NN_QPT 8          // queries per thread (8-way ILP)
#define NN_CSL 128        // candidates per slice
#define NN_BLOCKS 256
// gather/solve: 128 blocks x 64 threads = 8192 (1 query per thread)
#define GS_BLOCKS 128
#define GS_T 64
#define ACC_PAD 8         // one f64 per 64B line

struct IcpCtl {
  double err;
  double Rc[9];     // cumulative rotation (row-major): pc = Rc*p1 + tc
  double tc[3];
  int done;
};

// ---------------------------------------------------------------------------
// prep: p2aug, nn sentinels, padded acc/tickets zeroed, ctl reset
// ---------------------------------------------------------------------------
__global__ __launch_bounds__(256) void icp_prep(const float* __restrict__ p2,
                                                float4* __restrict__ p2aug,
                                                unsigned long long* __restrict__ nn,
                                                IcpCtl* __restrict__ ctl,
                                                double* __restrict__ acc,
                                                unsigned* __restrict__ gtick,
                                                unsigned* __restrict__ root) {
  int t = blockIdx.x * 256 + threadIdx.x;   // grid covers exactly N_PTS
  float x = p2[3*t], y = p2[3*t+1], z = p2[3*t+2];
  p2aug[t] = make_float4(x, y, z, fmaf(x, x, fmaf(y, y, z*z)));
  nn[t] = ~0ull;
  if (t < 256 * ACC_PAD) acc[t] = 0.0;      // 256 padded slots
  if (t < 256) gtick[t] = 0u;               // padded ticket array
  if (t == 0) {
    *root = 0u;
    ctl->err = 0.0; ctl->done = 0;
    #pragma unroll
    for (int i = 0; i < 9; ++i) ctl->Rc[i] = (i % 4 == 0) ? 1.0 : 0.0;
    ctl->tc[0] = ctl->tc[1] = ctl->tc[2] = 0.0;
  }
}

// ---------------------------------------------------------------------------
// NN search (R13-proven, small blocks launch fast). Each thread owns 8
// queries, scans 128 LDS-staged candidates. Cross-block argmin via relaxed
// memory-side atomicMin on packed (ordered-float(d2'), idx) u64 -> lowest
// distance then lowest index (jnp.argmin tie semantics).
// ---------------------------------------------------------------------------
__global__ __launch_bounds__(256) void icp_nn(const float* __restrict__ p1,
                                              const float4* __restrict__ p2aug,
                                              unsigned long long* __restrict__ nn,
                                              const IcpCtl* __restrict__ ctl) {
  if (ctl->done) return;                     // uniform across grid
  __shared__ float4 cand[NN_CSL];
  const int tid = threadIdx.x;
  const int qg  = blockIdx.x >> 6;           // 0..3
  const int cs  = blockIdx.x & 63;           // 0..63
  const int c0  = cs * NN_CSL;
  if (tid < NN_CSL) cand[tid] = p2aug[c0 + tid];

  const double R0 = ctl->Rc[0], R1 = ctl->Rc[1], R2 = ctl->Rc[2];
  const double R3 = ctl->Rc[3], R4 = ctl->Rc[4], R5 = ctl->Rc[5];
  const double R6 = ctl->Rc[6], R7 = ctl->Rc[7], R8 = ctl->Rc[8];
  const double T0 = ctl->tc[0], T1 = ctl->tc[1], T2 = ctl->tc[2];

  float ax[NN_QPT], ay[NN_QPT], az[NN_QPT], best[NN_QPT];
  int bidx[NN_QPT];
  const int qbase = (qg << 11) + tid;        // qg*2048 + tid
  #pragma unroll
  for (int j = 0; j < NN_QPT; ++j) {
    const int q = qbase + (j << 8);
    const double X = (double)p1[3*q], Y = (double)p1[3*q+1], Z = (double)p1[3*q+2];
    const float qx = (float)(R0*X + R1*Y + R2*Z + T0);  // fp32-rounded (ref pc)
    const float qy = (float)(R3*X + R4*Y + R5*Z + T1);
    const float qz = (float)(R6*X + R7*Y + R8*Z + T2);
    ax[j] = -2.f*qx; ay[j] = -2.f*qy; az[j] = -2.f*qz;
    best[j] = __builtin_inff(); bidx[j] = 0;
  }
  __syncthreads();

  #pragma unroll 4
  for (int i = 0; i < NN_CSL; ++i) {
    float4 c = cand[i];
    #pragma unroll
    for (int j = 0; j < NN_QPT; ++j) {
      float d = fmaf(ax[j], c.x, fmaf(ay[j], c.y, fmaf(az[j], c.z, c.w)));
      if (d < best[j]) { best[j] = d; bidx[j] = c0 + i; }
    }
  }
  #pragma unroll
  for (int j = 0; j < NN_QPT; ++j) {
    unsigned u = __float_as_uint(best[j]);
    u ^= (unsigned)((int)u >> 31) | 0x80000000u;   // monotone float->uint map
    atomicMin(nn + qbase + (j << 8),
              ((unsigned long long)u << 32) | (unsigned)bidx[j]);
  }
}

// ---------------------------------------------------------------------------
// Register-only 3x3 Kabsch from raw sums (no runtime-indexed reg arrays).
// s[0]=sum dmin, s[1..3]=sum src, s[4..6]=sum dst, s[7..15]=sum src_i*dst_j.
// R = V diag(1,1,detV) U~^T (right-handed U~) == reference's sign-fixed SVD.
// ---------------------------------------------------------------------------
__device__ __forceinline__ void kabsch_solve(const double* s, double* R, double* T) {
  const double n = (double)N_PTS;
  const double c1x = s[1]/n, c1y = s[2]/n, c1z = s[3]/n;
  const double c2x = s[4]/n, c2y = s[5]/n, c2z = s[6]/n;
  const double h00 = s[7]  - n*c1x*c2x, h01 = s[8]  - n*c1x*c2y, h02 = s[9]  - n*c1x*c2z;
  const double h10 = s[10] - n*c1y*c2x, h11 = s[11] - n*c1y*c2y, h12 = s[12] - n*c1y*c2z;
  const double h20 = s[13] - n*c1z*c2x, h21 = s[14] - n*c1z*c2y, h22 = s[15] - n*c1z*c2z;

  double a00 = h00*h00 + h10*h10 + h20*h20;
  double a01 = h00*h01 + h10*h11 + h20*h21;
  double a02 = h00*h02 + h10*h12 + h20*h22;
  double a11 = h01*h01 + h11*h11 + h21*h21;
  double a12 = h01*h02 + h11*h12 + h21*h22;
  double a22 = h02*h02 + h12*h12 + h22*h22;

  double v00=1.0, v01=0.0, v02=0.0;
  double v10=0.0, v11=1.0, v12=0.0;
  double v20=0.0, v21=0.0, v22=1.0;

#define ROT3(app, aqq, apq, arp, arq, vpa, vqa, vpb, vqb, vpc, vqc)              \
  {                                                                              \
    double apq_ = apq;                                                           \
    if (fabs(apq_) > 1e-300) {                                                   \
      double tau = (aqq - app) / (2.0 * apq_);                                   \
      double tt  = (tau >= 0.0 ? 1.0 : -1.0) / (fabs(tau) + sqrt(1.0 + tau*tau));\
      double c_  = 1.0 / sqrt(1.0 + tt*tt), sn = tt * c_;                        \
      app -= tt * apq_;  aqq += tt * apq_;  apq = 0.0;                           \
      double t1 = arp, t2 = arq;                                                 \
      arp = c_*t1 - sn*t2;  arq = sn*t1 + c_*t2;                                 \
      t1 = vpa; t2 = vqa; vpa = c_*t1 - sn*t2; vqa = sn*t1 + c_*t2;              \
      t1 = vpb; t2 = vqb; vpb = c_*t1 - sn*t2; vqb = sn*t1 + c_*t2;              \
      t1 = vpc; t2 = vqc; vpc = c_*t1 - sn*t2; vqc = sn*t1 + c_*t2;              \
    }                                                                            \
  }

  #pragma unroll
  for (int sweep = 0; sweep < 6; ++sweep) {
    ROT3(a00, a11, a01, a02, a12, v00, v01, v10, v11, v20, v21);  // (0,1)
    ROT3(a00, a22, a02, a01, a12, v00, v02, v10, v12, v20, v22);  // (0,2)
    ROT3(a11, a22, a12, a01, a02, v01, v02, v11, v12, v21, v22);  // (1,2)
  }
#undef ROT3

  double l0 = a00, l1 = a11, l2 = a22;
  double e0x=v00, e0y=v10, e0z=v20;
  double e1x=v01, e1y=v11, e1z=v21;
  double e2x=v02, e2y=v12, e2z=v22;
#define CSWAP(la, lb, xa, ya, za, xb, yb, zb)                                    \
  if (lb > la) { double t_;                                                      \
    t_ = la; la = lb; lb = t_;  t_ = xa; xa = xb; xb = t_;                       \
    t_ = ya; ya = yb; yb = t_;  t_ = za; za = zb; zb = t_; }
  CSWAP(l0, l1, e0x, e0y, e0z, e1x, e1y, e1z);
  CSWAP(l0, l2, e0x, e0y, e0z, e2x, e2y, e2z);
  CSWAP(l1, l2, e1x, e1y, e1z, e2x, e2y, e2z);
#undef CSWAP

  double detV = e0x*(e1y*e2z - e1z*e2y) - e0y*(e1x*e2z - e1z*e2x)
              + e0z*(e1x*e2y - e1y*e2x);
  const double dsg = (detV >= 0.0) ? 1.0 : -1.0;

  double u0x = h00*e0x + h01*e0y + h02*e0z;
  double u0y = h10*e0x + h11*e0y + h12*e0z;
  double u0z = h20*e0x + h21*e0y + h22*e0z;
  double n0 = sqrt(u0x*u0x + u0y*u0y + u0z*u0z);
  if (!(n0 > 1e-150)) {
    R[0]=1.0; R[1]=0.0; R[2]=0.0; R[3]=0.0; R[4]=1.0; R[5]=0.0;
    R[6]=0.0; R[7]=0.0; R[8]=1.0;
    T[0]=c2x-c1x; T[1]=c2y-c1y; T[2]=c2z-c1z;
    return;
  }
  u0x /= n0; u0y /= n0; u0z /= n0;
  double u1x = h00*e1x + h01*e1y + h02*e1z;
  double u1y = h10*e1x + h11*e1y + h12*e1z;
  double u1z = h20*e1x + h21*e1y + h22*e1z;
  const double d10 = u1x*u0x + u1y*u0y + u1z*u0z;
  u1x -= d10*u0x; u1y -= d10*u0y; u1z -= d10*u0z;
  double n1 = sqrt(u1x*u1x + u1y*u1y + u1z*u1z);
  if (!(n1 > 1e-150)) {
    R[0]=1.0; R[1]=0.0; R[2]=0.0; R[3]=0.0; R[4]=1.0; R[5]=0.0;
    R[6]=0.0; R[7]=0.0; R[8]=1.0;
    T[0]=c2x-c1x; T[1]=c2y-c1y; T[2]=c2z-c1z;
    return;
  }
  u1x /= n1; u1y /= n1; u1z /= n1;
  const double u2x = u0y*u1z - u0z*u1y;
  const double u2y = u0z*u1x - u0x*u1z;
  const double u2z = u0x*u1y - u0y*u1x;

  R[0] = e0x*u0x + e1x*u1x + dsg*e2x*u2x;
  R[1] = e0x*u0y + e1x*u1y + dsg*e2x*u2y;
  R[2] = e0x*u0z + e1x*u1z + dsg*e2x*u2z;
  R[3] = e0y*u0x + e1y*u1x + dsg*e2y*u2x;
  R[4] = e0y*u0y + e1y*u1y + dsg*e2y*u2y;
  R[5] = e0y*u0z + e1y*u1z + dsg*e2y*u2z;
  R[6] = e0z*u0x + e1z*u1x + dsg*e2z*u2x;
  R[7] = e0z*u0y + e1z*u1y + dsg*e2z*u2y;
  R[8] = e0z*u0z + e1z*u1z + dsg*e2z*u2z;
  T[0] = c2x - (R[0]*c1x + R[1]*c1y + R[2]*c1z);
  T[1] = c2y - (R[3]*c1x + R[4]*c1y + R[5]*c1z);
  T[2] = c2z - (R[6]*c1x + R[7]*c1y + R[8]*c1z);
}

// ---------------------------------------------------------------------------
// gather+solve: 128 small blocks (64 thr), 1 query/thread. Plain-load nn[q]
// spread over 128 CUs (parallel L3 fetch -> kills R13's 43us single-block
// readback), reset sentinel, pair sums (named scalars), wave-reduce, then
// line-padded atomic tree (8 adds/line, 8-way tickets). Root-last block:
// RMW-read 256 padded lines, register Kabsch, compose, out, reset.
// ---------------------------------------------------------------------------
__global__ __launch_bounds__(GS_T) void icp_gsolve(
    const float* __restrict__ p1, const float4* __restrict__ p2aug,
    unsigned long long* __restrict__ nn, IcpCtl* __restrict__ ctl,
    double* __restrict__ acc, unsigned* __restrict__ gtick,
    unsigned* __restrict__ root, float* __restrict__ out) {
  if (ctl->done) return;                    // uniform
  __shared__ int sflag;
  __shared__ double totLds[16];
  const int tid = threadIdx.x;              // 0..63 (one wave)
  const int bid = blockIdx.x;               // 0..127
  const int q   = (bid << 6) + tid;
  if (tid == 0) sflag = 0;

  const double R0 = ctl->Rc[0], R1 = ctl->Rc[1], R2 = ctl->Rc[2];
  const double R3 = ctl->Rc[3], R4 = ctl->Rc[4], R5 = ctl->Rc[5];
  const double R6 = ctl->Rc[6], R7 = ctl->Rc[7], R8 = ctl->Rc[8];
  const double T0 = ctl->tc[0], T1 = ctl->tc[1], T2 = ctl->tc[2];

  const unsigned long long m = nn[q];       // plain load (coalesced)
  nn[q] = ~0ull;                            // reset for next iteration
  const unsigned idx = (unsigned)(m & 0xffffffffull);

  const double X = (double)p1[3*q], Y = (double)p1[3*q+1], Z = (double)p1[3*q+2];
  // fp32-rounded source position (bit-identical to what NN used / ref's pc)
  const float sxf = (float)(R0*X + R1*Y + R2*Z + T0);
  const float syf = (float)(R3*X + R4*Y + R5*Z + T1);
  const float szf = (float)(R6*X + R7*Y + R8*Z + T2);
  const float4 b4 = p2aug[idx];
  const double ax = sxf, ay = syf, az = szf;
  const double bx = b4.x, by = b4.y, bz = b4.z;
  const double d2 = (ax*ax + ay*ay + az*az) + (bx*bx + by*by + bz*bz)
                  - 2.0*(ax*bx + ay*by + az*bz);
  double v0  = sqrt(fmax(d2, 1e-12));
  double v1  = ax,    v2  = ay,    v3  = az;
  double v4  = bx,    v5  = by,    v6  = bz;
  double v7  = ax*bx, v8  = ax*by, v9  = ax*bz;
  double v10 = ay*bx, v11 = ay*by, v12 = ay*bz;
  double v13 = az*bx, v14 = az*by, v15 = az*bz;

  // wave reduce (named scalars; lane 0 ends with each total)
#define WR(v) { for (int o = 32; o > 0; o >>= 1) v += __shfl_down(v, o, 64); }
  WR(v0) WR(v1) WR(v2) WR(v3) WR(v4) WR(v5) WR(v6) WR(v7)
  WR(v8) WR(v9) WR(v10) WR(v11) WR(v12) WR(v13) WR(v14) WR(v15)
#undef WR

  if (tid == 0) {
    const int setb = (bid & 15) << 4;       // set base (value slots 0..15)
    atomicAdd(acc + (setb + 0)  * ACC_PAD, v0);
    atomicAdd(acc + (setb + 1)  * ACC_PAD, v1);
    atomicAdd(acc + (setb + 2)  * ACC_PAD, v2);
    atomicAdd(acc + (setb + 3)  * ACC_PAD, v3);
    atomicAdd(acc + (setb + 4)  * ACC_PAD, v4);
    atomicAdd(acc + (setb + 5)  * ACC_PAD, v5);
    atomicAdd(acc + (setb + 6)  * ACC_PAD, v6);
    atomicAdd(acc + (setb + 7)  * ACC_PAD, v7);
    atomicAdd(acc + (setb + 8)  * ACC_PAD, v8);
    atomicAdd(acc + (setb + 9)  * ACC_PAD, v9);
    atomicAdd(acc + (setb + 10) * ACC_PAD, v10);
    atomicAdd(acc + (setb + 11) * ACC_PAD, v11);
    atomicAdd(acc + (setb + 12) * ACC_PAD, v12);
    atomicAdd(acc + (setb + 13) * ACC_PAD, v13);
    atomicAdd(acc + (setb + 14) * ACC_PAD, v14);
    atomicAdd(acc + (setb + 15) * ACC_PAD, v15);
    // this wave issued the adds: wait completion acks, then arrive
    asm volatile("s_waitcnt vmcnt(0)" ::: "memory");
    unsigned og = atomicAdd(gtick + ((bid & 15) << 4), 1u);  // 8-way
    if (og == 7u) {                         // last of the 8 blocks in set
      unsigned orr = atomicAdd(root, 1u);   // 16-way
      if (orr == 15u) sflag = 1;            // last overall -> solver
    }
  }
  __syncthreads();
  if (!sflag) return;

  // ---- solver: value v total = sum over 16 sets (RMW-reads, padded) ----
  if (tid < 16) {
    double tot = 0.0;
    for (int s2 = 0; s2 < 16; ++s2)
      tot += atomicAdd(acc + ((s2 << 4) + tid) * ACC_PAD, 0.0);
    totLds[tid] = tot;
  }
  __syncthreads();

  if (tid == 0) {
    double sm[16];
    #pragma unroll
    for (int i = 0; i < 16; ++i) sm[i] = totLds[i];
    double R[9], T[3];
    kabsch_solve(sm, R, T);
    // compose: pc_new = R*(Rc*p1 + tc) + T = (R*Rc)*p1 + (R*tc + T)
    double Rc[9] = {R0,R1,R2,R3,R4,R5,R6,R7,R8};
    double tc[3] = {T0,T1,T2};
    double Rn[9], tn[3];
    #pragma unroll
    for (int i = 0; i < 3; ++i) {
      #pragma unroll
      for (int j = 0; j < 3; ++j)
        Rn[3*i+j] = R[3*i+0]*Rc[0+j] + R[3*i+1]*Rc[3+j] + R[3*i+2]*Rc[6+j];
      tn[i] = R[3*i+0]*tc[0] + R[3*i+1]*tc[1] + R[3*i+2]*tc[2] + T[i];
    }
    #pragma unroll
    for (int i = 0; i < 9; ++i) ctl->Rc[i] = Rn[i];
    #pragma unroll
    for (int i = 0; i < 3; ++i) ctl->tc[i] = tn[i];
    const double errnew = sm[0];            // B == 1
    ctl->done = (fabs(ctl->err - errnew) < ICP_TOL) ? 1 : 0;
    ctl->err  = errnew;
    // out = [Rc | tc] 3x4 (kabsch(p1, Rc*p1+tc) == (Rc,tc) exactly).
    #pragma unroll
    for (int i = 0; i < 3; ++i) {
      out[4*i + 0] = (float)Rn[3*i + 0];
      out[4*i + 1] = (float)Rn[3*i + 1];
      out[4*i + 2] = (float)Rn[3*i + 2];
      out[4*i + 3] = (float)tn[i];
    }
    *root = 0u;                             // reset root
  }
  // reset acc (256 padded slots) + group tickets; boundary publishes
  #pragma unroll
  for (int r = 0; r < 4; ++r) acc[((r << 6) + tid) * ACC_PAD] = 0.0;
  if (tid < 16) gtick[tid << 4] = 0u;
}

// ---------------------------------------------------------------------------
extern "C" void kernel_launch(void* const* d_in, const int* in_sizes, int n_in,
                              void* d_out, int out_size, void* d_ws, size_t ws_size,
                              hipStream_t stream) {
  const float* p1 = (const float*)d_in[0];
  const float* p2 = (const float*)d_in[1];
  float* out = (float*)d_out;

  char* ws = (char*)d_ws;
  float4* p2aug = (float4*)ws;                                // 128 KiB
  unsigned long long* nn = (unsigned long long*)(ws + 128*1024);  // 64 KiB
  IcpCtl* ctl   = (IcpCtl*)(ws + 192*1024);                   // ~112 B
  double* acc   = (double*)(ws + 196*1024);                   // 16 KiB padded
  unsigned* gtick = (unsigned*)(ws + 212*1024);               // 1 KiB padded
  unsigned* root  = (unsigned*)(ws + 216*1024);               // 1 line

  icp_prep<<<N_PTS/256, 256, 0, stream>>>(p2, p2aug, nn, ctl, acc, gtick, root);
  for (int it = 0; it < ICP_STEPS; ++it) {
    icp_nn<<<NN_BLOCKS, 256, 0, stream>>>(p1, p2aug, nn, ctl);
    icp_gsolve<<<GS_BLOCKS, GS_T, 0, stream>>>(p1, p2aug, nn, ctl,
                                               acc, gtick, root, out);
  }
}